// Round 3
// baseline (180.245 us; speedup 1.0000x reference)
//
#include <hip/hip_runtime.h>
#include <cstdint>

#define BATCH 16
#define SEQ 2048
#define EMB 512
#define FFN 2048
#define NQ 8
#define M_TOTAL (BATCH * SEQ)   // 32768

#define BM 128
#define BN 256
#define BK 32
#define NTHREADS 512            // 8 waves: 2 (m) x 4 (n), wave tile 64x64

typedef __attribute__((ext_vector_type(8))) short short8;   // 8 bf16 (MFMA A/B frag)
typedef __attribute__((ext_vector_type(4))) float float4v;  // MFMA C/D frag
typedef __attribute__((ext_vector_type(4))) unsigned int uint4v;

// fp32 -> bf16 bits, round-to-nearest-even (finite inputs)
static __device__ __forceinline__ unsigned int f2bf(float f) {
    unsigned int u = __builtin_bit_cast(unsigned int, f);
    return (u + 0x7fffu + ((u >> 16) & 1u)) >> 16;
}
static __device__ __forceinline__ unsigned int f2bf_pk(float lo, float hi) {
    return f2bf(lo) | (f2bf(hi) << 16);
}

// ---- prep: W2 fp32 -> bf16 (row-major [EMB][FFN], K-contiguous) ----
__global__ __launch_bounds__(256) void prep_w2(const float* __restrict__ W2,
                                               unsigned int* __restrict__ w2b) {
    int idx = (blockIdx.x * 256 + threadIdx.x) * 4;
    float4 v = *(const float4*)&W2[idx];
    w2b[idx / 2]     = f2bf_pk(v.x, v.y);
    w2b[idx / 2 + 1] = f2bf_pk(v.z, v.w);
}

// Swizzled LDS tile layout: row stride 32 bf16 (64 B = 4 chunks of 16 B).
// Logical k-chunk q lives at physical chunk q ^ ((row>>1)&3).
//
// v4: round-1 geometry + 8-phase-style schedule (T3+T4+T5):
//   per K-tile t, two sub-phases X/Y, each {pre: ds_reads+hgen-half |
//   s_barrier | lgkmcnt(0) | setprio(1) [stageB issue] 8 MFMA [vmcnt(2)]
//   setprio(0) | s_barrier}. Raw barriers (no vmcnt(0) drain); B-tile DMA
//   issued in X(t) is drained by vmcnt(2) in X(t+1) -> stays in flight
//   across 4 barriers. 2 blocks/CU interleave across each other's barriers.

__global__ __launch_bounds__(NTHREADS, 4) void ffq_main(
    const float* __restrict__ x,              // [M_TOTAL][EMB], cols 0..7 used
    const float* __restrict__ theta,          // [8]
    const float* __restrict__ W1,             // [FFN][8] fp32
    const unsigned short* __restrict__ w2b,   // [EMB][FFN] bf16 bits
    float* __restrict__ out)                  // [M_TOTAL][EMB]
{
    __shared__ unsigned short Asm[2][BM * BK];   // 2 x 8 KB  h tile, swizzled
    __shared__ unsigned short Bsm[2][BN * BK];   // 2 x 16 KB W2 tile, swizzled
    __shared__ unsigned short w1s[FFN * NQ];     // 32 KB whole W1 bf16 [f][j]
    // total 80 KB -> 2 blocks/CU

    const int t    = threadIdx.x;
    const int m0   = blockIdx.x * BM;
    const int n0   = blockIdx.y * BN;
    const int wave = t >> 6, lane = t & 63;
    const int quad = lane >> 4, l16 = lane & 15;
    const int wm   = wave >> 2, wn = wave & 3;

    // ---- stage whole W1 -> bf16 LDS ----
#pragma unroll
    for (int i = 0; i < (FFN * NQ / 2) / NTHREADS; ++i) {   // 16 iters
        int p = i * NTHREADS + t;
        float2 v = *(const float2*)&W1[p * 2];
        *(unsigned int*)&w1s[p * 2] = f2bf_pk(v.x, v.y);
    }

    // ---- per-wave persistent Q fragment (B-operand of h-gen MFMA) ----
    short8 qfrag;
    {
        int qrow = m0 + wave * 16 + l16;
        const float* xr = x + (size_t)qrow * EMB;
        float4 xa = *(const float4*)xr;
        float4 xb = *(const float4*)(xr + 4);
        uint4v uq;
        uq[0] = f2bf_pk(__cosf(2.f * xa.x + theta[0]), __cosf(2.f * xa.y + theta[1]));
        uq[1] = f2bf_pk(__cosf(2.f * xa.z + theta[2]), __cosf(2.f * xa.w + theta[3]));
        uq[2] = f2bf_pk(__cosf(2.f * xb.x + theta[4]), __cosf(2.f * xb.y + theta[5]));
        uq[3] = f2bf_pk(__cosf(2.f * xb.z + theta[6]), __cosf(2.f * xb.w + theta[7]));
        qfrag = __builtin_bit_cast(short8, uq);
        if (quad != 0) qfrag = (short8)0;
    }

    // ---- per-thread B-staging constants (chunk -> source-swizzled gaddr) ----
    const int c0 = t, c1 = NTHREADS + t;
    const int n0c0 = c0 >> 2, s0c = c0 & 3;
    const int n0c1 = c1 >> 2, s1c = c1 & 3;
    const unsigned short* gB0 =
        w2b + (size_t)(n0 + n0c0) * FFN + (s0c ^ ((n0c0 >> 1) & 3)) * 8;
    const unsigned short* gB1 =
        w2b + (size_t)(n0 + n0c1) * FFN + (s1c ^ ((n0c1 >> 1) & 3)) * 8;

    auto stageB = [&](int k0, int buf) __attribute__((always_inline)) {
        __builtin_amdgcn_global_load_lds(
            (const __attribute__((address_space(1))) unsigned int*)(gB0 + k0),
            (__attribute__((address_space(3))) unsigned int*)(uintptr_t)(&Bsm[buf][c0 * 8]),
            16, 0, 0);
        __builtin_amdgcn_global_load_lds(
            (const __attribute__((address_space(1))) unsigned int*)(gB1 + k0),
            (__attribute__((address_space(3))) unsigned int*)(uintptr_t)(&Bsm[buf][c1 * 8]),
            16, 0, 0);
    };

    // h-gen HALF fh for K-rows [kh, kh+32): 1 w1 read + 1 MFMA + pack + 1 write
    const int hswz = (l16 >> 1) & 3;
    const int hm   = wave * 16 + l16;
    auto hgenH = [&](int kh, int buf, int fh) __attribute__((always_inline)) {
        int f = kh + fh * 16 + l16;
        short8 w1f = *(const short8*)&w1s[f * NQ];
        float4v hc = __builtin_amdgcn_mfma_f32_16x16x32_bf16(
            w1f, qfrag, (float4v)0.0f, 0, 0, 0);
        unsigned int p0 = f2bf_pk(fmaxf(hc[0], 0.f), fmaxf(hc[1], 0.f));
        unsigned int p1 = f2bf_pk(fmaxf(hc[2], 0.f), fmaxf(hc[3], 0.f));
        int qph = (fh * 2 + (quad >> 1)) ^ hswz;
        unsigned long long pk = ((unsigned long long)p1 << 32) | p0;
        *(unsigned long long*)&Asm[buf][hm * 32 + qph * 8 + (quad & 1) * 4] = pk;
    };

    float4v acc[16];
#pragma unroll
    for (int i = 0; i < 16; ++i) acc[i] = (float4v)0.0f;

    short8 af[4], bf01[2], bf23[2];

    auto readAf = [&](int buf) __attribute__((always_inline)) {
#pragma unroll
        for (int fm = 0; fm < 4; ++fm) {
            int row = wm * 64 + fm * 16 + l16;
            int qph = quad ^ ((row >> 1) & 3);
            af[fm] = *(const short8*)&Asm[buf][row * 32 + qph * 8];
        }
    };
    auto readB01 = [&](int buf) __attribute__((always_inline)) {
#pragma unroll
        for (int fn = 0; fn < 2; ++fn) {
            int row = wn * 64 + fn * 16 + l16;
            int qph = quad ^ ((row >> 1) & 3);
            bf01[fn] = *(const short8*)&Bsm[buf][row * 32 + qph * 8];
        }
    };
    auto readB23 = [&](int buf) __attribute__((always_inline)) {
#pragma unroll
        for (int fn = 0; fn < 2; ++fn) {
            int row = wn * 64 + (fn + 2) * 16 + l16;
            int qph = quad ^ ((row >> 1) & 3);
            bf23[fn] = *(const short8*)&Bsm[buf][row * 32 + qph * 8];
        }
    };

#define FENCE() asm volatile("" ::: "memory")
#define BAR()   do { FENCE(); __builtin_amdgcn_s_barrier(); FENCE(); } while (0)
#define LGKM0() do { asm volatile("s_waitcnt lgkmcnt(0)" ::: "memory"); \
                     __builtin_amdgcn_sched_barrier(0); } while (0)

    // X phase of tile tt (parity cb): compute fn01(tt), produce h(tt+1) half 0,
    // issue B(tt+2), drain B(tt+1) with counted vmcnt.
    auto phaseX = [&](int tt, int cb, bool dostage, bool dohg, int vmode)
        __attribute__((always_inline)) {
        readAf(cb);
        readB23(cb);
        if (dohg) hgenH((tt + 1) * BK, 1 - cb, 0);
        BAR();
        LGKM0();
        __builtin_amdgcn_s_setprio(1);
        if (dostage) stageB((tt + 2) * BK, cb);
#pragma unroll
        for (int fm = 0; fm < 4; ++fm)
#pragma unroll
            for (int fn = 0; fn < 2; ++fn)
                acc[fm * 4 + fn] = __builtin_amdgcn_mfma_f32_16x16x32_bf16(
                    af[fm], bf01[fn], acc[fm * 4 + fn], 0, 0, 0);
        if (vmode == 2)      asm volatile("s_waitcnt vmcnt(2)" ::: "memory");
        else if (vmode == 0) asm volatile("s_waitcnt vmcnt(0)" ::: "memory");
        __builtin_amdgcn_s_setprio(0);
        BAR();
    };
    // Y phase of tile tt: compute fn23(tt), read bf01(tt+1), produce h(tt+1) half 1.
    auto phaseY = [&](int tt, int cb, bool dord, bool dohg)
        __attribute__((always_inline)) {
        if (dord) readB01(1 - cb);
        if (dohg) hgenH((tt + 1) * BK, 1 - cb, 1);
        BAR();
        LGKM0();
        __builtin_amdgcn_s_setprio(1);
#pragma unroll
        for (int fm = 0; fm < 4; ++fm)
#pragma unroll
            for (int fn = 0; fn < 2; ++fn)
                acc[fm * 4 + 2 + fn] = __builtin_amdgcn_mfma_f32_16x16x32_bf16(
                    af[fm], bf23[fn], acc[fm * 4 + 2 + fn], 0, 0, 0);
        __builtin_amdgcn_s_setprio(0);
        BAR();
    };

    // ---- prologue ----
    asm volatile("s_waitcnt lgkmcnt(0)" ::: "memory");
    BAR();                       // w1s visible to all waves
    stageB(0, 0);
    stageB(1 * BK, 1);
    hgenH(0, 0, 0);
    hgenH(0, 0, 1);
    asm volatile("s_waitcnt vmcnt(0) lgkmcnt(0)" ::: "memory");
    BAR();                       // B(0),B(1) landed; h(0) visible
    readB01(0);                  // bf01(0)  (the "Y(-1)" read)

    // ---- main loop: tiles 0..61, pair-unrolled for literal parity ----
    for (int kt = 0; kt < 62; kt += 2) {
        phaseX(kt,     0, true, true, 2);
        phaseY(kt,     0, true, true);
        phaseX(kt + 1, 1, true, true, 2);
        phaseY(kt + 1, 1, true, true);
    }
    // tile 62 (c=0): no stageB(64); full drain so bf01(63) is safe
    phaseX(62, 0, false, true, 0);
    phaseY(62, 0, true,  true);
    // tile 63 (c=1): compute only
    phaseX(63, 1, false, false, -1);
    phaseY(63, 1, false, false);

    // ---- epilogue: D layout col=lane&15 (n), row=quad*4+reg (m) ----
    const int om = m0 + wm * 64;
    const int on = n0 + wn * 64;
#pragma unroll
    for (int fm = 0; fm < 4; ++fm) {
#pragma unroll
        for (int fn = 0; fn < 4; ++fn) {
            float4v v = acc[fm * 4 + fn];
            int rbase = om + fm * 16 + quad * 4;
            int c     = on + fn * 16 + l16;
#pragma unroll
            for (int r = 0; r < 4; ++r)
                out[(size_t)(rbase + r) * EMB + c] = v[r];
        }
    }
}

extern "C" void kernel_launch(void* const* d_in, const int* in_sizes, int n_in,
                              void* d_out, int out_size, void* d_ws, size_t ws_size,
                              hipStream_t stream) {
    const float* x     = (const float*)d_in[0];
    const float* theta = (const float*)d_in[1];
    const float* W1    = (const float*)d_in[2];
    const float* W2    = (const float*)d_in[3];
    float* out = (float*)d_out;

    unsigned int* w2b = (unsigned int*)d_ws;   // 2 MiB of ws (bf16 bits, packed)

    prep_w2<<<(EMB * FFN) / (256 * 4), 256, 0, stream>>>(W2, w2b);

    dim3 grid(M_TOTAL / BM, EMB / BN);         // 256 x 2 = 512 blocks, 2/CU
    ffq_main<<<grid, NTHREADS, 0, stream>>>(x, theta, W1, (const unsigned short*)w2b, out);
}

// Round 4
// 176.496 us; speedup vs baseline: 1.0212x; 1.0212x over previous
//
#include <hip/hip_runtime.h>
#include <cstdint>

#define BATCH 16
#define SEQ 2048
#define EMB 512
#define FFN 2048
#define NQ 8
#define M_TOTAL (BATCH * SEQ)   // 32768

#define BM 128
#define BN 256
#define BK 32
#define NTHREADS 512            // 8 waves: 2 (m) x 4 (n), wave tile 64x64

typedef __attribute__((ext_vector_type(8))) short short8;   // 8 bf16 (MFMA A/B frag)
typedef __attribute__((ext_vector_type(4))) float float4v;  // MFMA C/D frag
typedef __attribute__((ext_vector_type(4))) unsigned int uint4v;

// fp32 -> bf16 bits, round-to-nearest-even (finite inputs) — host-side prep only
static __device__ __forceinline__ unsigned int f2bf(float f) {
    unsigned int u = __builtin_bit_cast(unsigned int, f);
    return (u + 0x7fffu + ((u >> 16) & 1u)) >> 16;
}
static __device__ __forceinline__ unsigned int f2bf_pk(float lo, float hi) {
    return f2bf(lo) | (f2bf(hi) << 16);
}
// single-instruction RTNE pack (hot path)
static __device__ __forceinline__ unsigned int cvt_pk_bf16(float lo, float hi) {
    unsigned int r;
    asm("v_cvt_pk_bf16_f32 %0, %1, %2" : "=v"(r) : "v"(lo), "v"(hi));
    return r;
}

// ---- prep: fp32 -> bf16 pairs (used for W2 [EMB][FFN] and W1 [FFN][NQ]) ----
__global__ __launch_bounds__(256) void prep_w2(const float* __restrict__ W2,
                                               unsigned int* __restrict__ w2b) {
    int idx = (blockIdx.x * 256 + threadIdx.x) * 4;
    float4 v = *(const float4*)&W2[idx];
    w2b[idx / 2]     = f2bf_pk(v.x, v.y);
    w2b[idx / 2 + 1] = f2bf_pk(v.z, v.w);
}

// Swizzled LDS tile layout: row stride 32 bf16 (64 B = 4 chunks of 16 B).
// Logical k-chunk q lives at physical chunk q ^ ((row>>1)&3) -> frag reads
// (row = base + l16, chunk = quad) cover all 32 banks per 8-lane phase.
//
// v5 = R2 structure (1 barrier/K-step, double buffer — best measured) +
//  (1) v_cvt_pk_bf16_f32 pack (was ~10 soft-float VALU ops each)
//  (2) W1 read from global bf16 (L1/L2-resident 32 KB) — w1s LDS removed,
//      -20% LDS-read traffic, LDS 80->48 KB/block
//  (3) hgen after compute: per-wave issue order = w1-load, stage-DMA,
//      frag-reads + 16 MFMA, hgen, barrier — w1 latency hides under compute.

__global__ __launch_bounds__(NTHREADS, 4) void ffq_main(
    const float* __restrict__ x,              // [M_TOTAL][EMB], cols 0..7 used
    const float* __restrict__ theta,          // [8]
    const unsigned short* __restrict__ w1b,   // [FFN][NQ] bf16 bits
    const unsigned short* __restrict__ w2b,   // [EMB][FFN] bf16 bits
    float* __restrict__ out)                  // [M_TOTAL][EMB]
{
    __shared__ unsigned short Asm[2][BM * BK];   // 2 x 8 KB  h tile, swizzled
    __shared__ unsigned short Bsm[2][BN * BK];   // 2 x 16 KB W2 tile, swizzled
    // total 48 KB -> 2 blocks/CU (reg-capped)

    const int t    = threadIdx.x;
    const int m0   = blockIdx.x * BM;
    const int n0   = blockIdx.y * BN;
    const int wave = t >> 6, lane = t & 63;
    const int quad = lane >> 4, l16 = lane & 15;
    const int wm   = wave >> 2, wn = wave & 3;

    // ---- per-wave persistent Q fragment (B-operand of h-gen MFMA) ----
    // wave g owns m rows g*16..g*16+15; lane l16 holds q[g*16+l16][j=0..7]
    // in quad 0 (K slots 0..7); quads 1..3 are ZERO so K=8..31 padding adds 0.
    short8 qfrag;
    {
        int qrow = m0 + wave * 16 + l16;
        const float* xr = x + (size_t)qrow * EMB;
        float4 xa = *(const float4*)xr;
        float4 xb = *(const float4*)(xr + 4);
        uint4v uq;
        uq[0] = f2bf_pk(__cosf(2.f * xa.x + theta[0]), __cosf(2.f * xa.y + theta[1]));
        uq[1] = f2bf_pk(__cosf(2.f * xa.z + theta[2]), __cosf(2.f * xa.w + theta[3]));
        uq[2] = f2bf_pk(__cosf(2.f * xb.x + theta[4]), __cosf(2.f * xb.y + theta[5]));
        uq[3] = f2bf_pk(__cosf(2.f * xb.z + theta[6]), __cosf(2.f * xb.w + theta[7]));
        qfrag = __builtin_bit_cast(short8, uq);
        if (quad != 0) qfrag = (short8)0;
    }

    // ---- per-thread B-staging constants (chunk -> source-swizzled gaddr) ----
    const int c0 = t, c1 = NTHREADS + t;
    const int n0c0 = c0 >> 2, s0c = c0 & 3;
    const int n0c1 = c1 >> 2, s1c = c1 & 3;
    const unsigned short* gB0 =
        w2b + (size_t)(n0 + n0c0) * FFN + (s0c ^ ((n0c0 >> 1) & 3)) * 8;
    const unsigned short* gB1 =
        w2b + (size_t)(n0 + n0c1) * FFN + (s1c ^ ((n0c1 >> 1) & 3)) * 8;

    auto stageB = [&](int k0, int buf) __attribute__((always_inline)) {
        __builtin_amdgcn_global_load_lds(
            (const __attribute__((address_space(1))) unsigned int*)(gB0 + k0),
            (__attribute__((address_space(3))) unsigned int*)(uintptr_t)(&Bsm[buf][c0 * 8]),
            16, 0, 0);
        __builtin_amdgcn_global_load_lds(
            (const __attribute__((address_space(1))) unsigned int*)(gB1 + k0),
            (__attribute__((address_space(3))) unsigned int*)(uintptr_t)(&Bsm[buf][c1 * 8]),
            16, 0, 0);
    };

    // W1 fragment loads for K-rows [kh, kh+32): 16 B/lane, L1/L2-resident
    auto loadW1 = [&](int kh, short8& a, short8& b) __attribute__((always_inline)) {
        a = *(const short8*)&w1b[(size_t)(kh + l16) * NQ];
        b = *(const short8*)&w1b[(size_t)(kh + 16 + l16) * NQ];
    };

    // h-gen via MFMA from register W1 frags, relu, cvt_pk -> swizzled Asm[buf]
    const int hswz = (l16 >> 1) & 3;
    const int hm   = wave * 16 + l16;
    auto hgen = [&](int buf, short8 w1f0, short8 w1f1) __attribute__((always_inline)) {
#pragma unroll
        for (int fh = 0; fh < 2; ++fh) {
            float4v hc = __builtin_amdgcn_mfma_f32_16x16x32_bf16(
                fh ? w1f1 : w1f0, qfrag, (float4v)0.0f, 0, 0, 0);
            unsigned int p0 = cvt_pk_bf16(fmaxf(hc[0], 0.f), fmaxf(hc[1], 0.f));
            unsigned int p1 = cvt_pk_bf16(fmaxf(hc[2], 0.f), fmaxf(hc[3], 0.f));
            int qph = (fh * 2 + (quad >> 1)) ^ hswz;
            unsigned long long pk = ((unsigned long long)p1 << 32) | p0;
            *(unsigned long long*)&Asm[buf][hm * 32 + qph * 8 + (quad & 1) * 4] = pk;
        }
    };

    float4v acc[16];
#pragma unroll
    for (int i = 0; i < 16; ++i) acc[i] = (float4v)0.0f;

    // conflict-free fragment loads + 16 MFMA from buffers [buf]
    auto compute = [&](int buf) __attribute__((always_inline)) {
        short8 af[4], bfr[4];
#pragma unroll
        for (int fm = 0; fm < 4; ++fm) {
            int row = wm * 64 + fm * 16 + l16;
            int qph = quad ^ ((row >> 1) & 3);
            af[fm] = *(const short8*)&Asm[buf][row * 32 + qph * 8];
        }
#pragma unroll
        for (int fn = 0; fn < 4; ++fn) {
            int row = wn * 64 + fn * 16 + l16;
            int qph = quad ^ ((row >> 1) & 3);
            bfr[fn] = *(const short8*)&Bsm[buf][row * 32 + qph * 8];
        }
        __builtin_amdgcn_s_setprio(1);
#pragma unroll
        for (int fm = 0; fm < 4; ++fm)
#pragma unroll
            for (int fn = 0; fn < 4; ++fn)
                acc[fm * 4 + fn] = __builtin_amdgcn_mfma_f32_16x16x32_bf16(
                    af[fm], bfr[fn], acc[fm * 4 + fn], 0, 0, 0);
        __builtin_amdgcn_s_setprio(0);
    };

    // ---- prologue: tile 0 ----
    {
        short8 w1f0, w1f1;
        loadW1(0, w1f0, w1f1);
        stageB(0, 0);
        hgen(0, w1f0, w1f1);
    }
    __syncthreads();        // vmcnt: B(0) landed; lgkm: h(0) visible

    // ---- pipelined main loop: 1 barrier per K-step ----
    // pair-unrolled so the buffer parity is a compile-time constant
    for (int kt = 0; kt < 62; kt += 2) {
        {   // step kt (cb=0): produce tile kt+1
            short8 w1f0, w1f1;
            loadW1((kt + 1) * BK, w1f0, w1f1);
            stageB((kt + 1) * BK, 1);
            compute(0);
            hgen(1, w1f0, w1f1);
        }
        __syncthreads();
        {   // step kt+1 (cb=1): produce tile kt+2
            short8 w1f0, w1f1;
            loadW1((kt + 2) * BK, w1f0, w1f1);
            stageB((kt + 2) * BK, 0);
            compute(1);
            hgen(0, w1f0, w1f1);
        }
        __syncthreads();
    }
    // kt = 62 (cb=0): produce last tile (63)
    {
        short8 w1f0, w1f1;
        loadW1(63 * BK, w1f0, w1f1);
        stageB(63 * BK, 1);
        compute(0);
        hgen(1, w1f0, w1f1);
    }
    __syncthreads();
    // kt = 63: tail, compute only
    compute(1);

    // ---- epilogue: D layout col=lane&15 (n), row=quad*4+reg (m) ----
    const int om = m0 + wm * 64;
    const int on = n0 + wn * 64;
#pragma unroll
    for (int fm = 0; fm < 4; ++fm) {
#pragma unroll
        for (int fn = 0; fn < 4; ++fn) {
            float4v v = acc[fm * 4 + fn];
            int rbase = om + fm * 16 + quad * 4;
            int c     = on + fn * 16 + l16;
#pragma unroll
            for (int r = 0; r < 4; ++r)
                out[(size_t)(rbase + r) * EMB + c] = v[r];
        }
    }
}

extern "C" void kernel_launch(void* const* d_in, const int* in_sizes, int n_in,
                              void* d_out, int out_size, void* d_ws, size_t ws_size,
                              hipStream_t stream) {
    const float* x     = (const float*)d_in[0];
    const float* theta = (const float*)d_in[1];
    const float* W1    = (const float*)d_in[2];
    const float* W2    = (const float*)d_in[3];
    float* out = (float*)d_out;

    unsigned int* w2b = (unsigned int*)d_ws;               // 2 MiB (bf16 bits)
    unsigned int* w1b = (unsigned int*)((char*)d_ws + (size_t)EMB * FFN * 2);  // 32 KB

    prep_w2<<<(EMB * FFN) / (256 * 4), 256, 0, stream>>>(W2, w2b);
    prep_w2<<<(FFN * NQ) / (256 * 4), 256, 0, stream>>>(W1, w1b);   // 16 blocks

    dim3 grid(M_TOTAL / BM, EMB / BN);         // 256 x 2 = 512 blocks, 2/CU
    ffq_main<<<grid, NTHREADS, 0, stream>>>(x, theta,
                                            (const unsigned short*)w1b,
                                            (const unsigned short*)w2b, out);
}

// Round 5
// 173.364 us; speedup vs baseline: 1.0397x; 1.0181x over previous
//
#include <hip/hip_runtime.h>
#include <cstdint>

#define BATCH 16
#define SEQ 2048
#define EMB 512
#define FFN 2048
#define NQ 8
#define M_TOTAL (BATCH * SEQ)   // 32768

#define BM 128
#define BN 256
#define BK 32
#define NTHREADS 256            // 4 waves: 2 (m) x 2 (n), wave tile 64x128

typedef __attribute__((ext_vector_type(8))) short short8;   // 8 bf16 (MFMA A/B frag)
typedef __attribute__((ext_vector_type(4))) float float4v;  // MFMA C/D frag
typedef __attribute__((ext_vector_type(4))) unsigned int uint4v;

// fp32 -> bf16 bits, round-to-nearest-even (finite inputs) — prep kernels only
static __device__ __forceinline__ unsigned int f2bf(float f) {
    unsigned int u = __builtin_bit_cast(unsigned int, f);
    return (u + 0x7fffu + ((u >> 16) & 1u)) >> 16;
}
static __device__ __forceinline__ unsigned int f2bf_pk(float lo, float hi) {
    return f2bf(lo) | (f2bf(hi) << 16);
}
// single-instruction RTNE pack (hot path)
static __device__ __forceinline__ unsigned int cvt_pk_bf16(float lo, float hi) {
    unsigned int r;
    asm("v_cvt_pk_bf16_f32 %0, %1, %2" : "=v"(r) : "v"(lo), "v"(hi));
    return r;
}

// ---- prep: fp32 -> bf16 pairs (used for W2 [EMB][FFN] and W1 [FFN][NQ]) ----
__global__ __launch_bounds__(256) void prep_w2(const float* __restrict__ W2,
                                               unsigned int* __restrict__ w2b) {
    int idx = (blockIdx.x * 256 + threadIdx.x) * 4;
    float4 v = *(const float4*)&W2[idx];
    w2b[idx / 2]     = f2bf_pk(v.x, v.y);
    w2b[idx / 2 + 1] = f2bf_pk(v.z, v.w);
}

// Swizzled LDS tile layout: row stride 32 bf16 (64 B = 4 chunks of 16 B).
// Logical k-chunk q lives at physical chunk q ^ ((row>>1)&3) -> frag reads
// (row = base + l16, chunk = quad) cover all 32 banks per 8-lane phase.
//
// v6 = v5 schedule (1 barrier/K-step, double buffer, hgen-after-compute) with
// a 64x128 wave tile in 4-wave blocks (2 blocks/CU):
//   - LDS fragment reads drop 512 -> 384 B per main MFMA (R4 counters showed
//     LDS data movement ~70% of the step — the binding pipe)
//   - two independent barrier domains per CU; each SIMD holds one wave from
//     each block -> phase-offset overlap (what R2's single 8-wave block lost)

__global__ __launch_bounds__(NTHREADS, 2) void ffq_main(
    const float* __restrict__ x,              // [M_TOTAL][EMB], cols 0..7 used
    const float* __restrict__ theta,          // [8]
    const unsigned short* __restrict__ w1b,   // [FFN][NQ] bf16 bits
    const unsigned short* __restrict__ w2b,   // [EMB][FFN] bf16 bits
    float* __restrict__ out)                  // [M_TOTAL][EMB]
{
    __shared__ unsigned short Asm[2][BM * BK];   // 2 x 8 KB  h tile, swizzled
    __shared__ unsigned short Bsm[2][BN * BK];   // 2 x 16 KB W2 tile, swizzled
    // total 48 KB -> 2 blocks/CU (reg-capped at 2 waves/SIMD)

    const int t    = threadIdx.x;
    const int m0   = blockIdx.x * BM;
    const int n0   = blockIdx.y * BN;
    const int wave = t >> 6, lane = t & 63;
    const int quad = lane >> 4, l16 = lane & 15;
    const int wm   = wave >> 1, wn = wave & 1;   // wave tile: m wm*64.., n wn*128..

    // ---- per-wave persistent Q fragments (B-operand of h-gen MFMA) ----
    // 4 waves must produce all BM=128 h rows -> 32 rows/wave (g2 = 0,1).
    // lane l16 holds q[wave*32+g2*16+l16][j=0..7] in quad 0; quads 1..3 zero.
    short8 qfrag[2];
#pragma unroll
    for (int g2 = 0; g2 < 2; ++g2) {
        int qrow = m0 + wave * 32 + g2 * 16 + l16;
        const float* xr = x + (size_t)qrow * EMB;
        float4 xa = *(const float4*)xr;
        float4 xb = *(const float4*)(xr + 4);
        uint4v uq;
        uq[0] = f2bf_pk(__cosf(2.f * xa.x + theta[0]), __cosf(2.f * xa.y + theta[1]));
        uq[1] = f2bf_pk(__cosf(2.f * xa.z + theta[2]), __cosf(2.f * xa.w + theta[3]));
        uq[2] = f2bf_pk(__cosf(2.f * xb.x + theta[4]), __cosf(2.f * xb.y + theta[5]));
        uq[3] = f2bf_pk(__cosf(2.f * xb.z + theta[6]), __cosf(2.f * xb.w + theta[7]));
        qfrag[g2] = __builtin_bit_cast(short8, uq);
        if (quad != 0) qfrag[g2] = (short8)0;
    }

    // ---- per-thread B-staging constants (chunk -> source-swizzled gaddr) ----
    // B tile = 1024 chunks of 16 B; 256 threads -> 4 chunks each.
    const unsigned short* gB[4];
#pragma unroll
    for (int i = 0; i < 4; ++i) {
        int c = i * NTHREADS + t;
        int n = c >> 2, s = c & 3;
        gB[i] = w2b + (size_t)(n0 + n) * FFN + (s ^ ((n >> 1) & 3)) * 8;
    }

    auto stageB = [&](int k0, int buf) __attribute__((always_inline)) {
#pragma unroll
        for (int i = 0; i < 4; ++i) {
            int c = i * NTHREADS + t;
            __builtin_amdgcn_global_load_lds(
                (const __attribute__((address_space(1))) unsigned int*)(gB[i] + k0),
                (__attribute__((address_space(3))) unsigned int*)(uintptr_t)(&Bsm[buf][c * 8]),
                16, 0, 0);
        }
    };

    // W1 fragment loads for K-rows [kh, kh+32): 16 B/lane, L1/L2-resident
    auto loadW1 = [&](int kh, short8& a, short8& b) __attribute__((always_inline)) {
        a = *(const short8*)&w1b[(size_t)(kh + l16) * NQ];
        b = *(const short8*)&w1b[(size_t)(kh + 16 + l16) * NQ];
    };

    // h-gen via MFMA from register W1 frags, relu, cvt_pk -> swizzled Asm[buf]
    // D layout: row quad*4+r -> f-offset fh*16+quad*4+r, col l16 -> m.
    const int hswz = (l16 >> 1) & 3;
    auto hgen = [&](int buf, short8 w1f0, short8 w1f1) __attribute__((always_inline)) {
#pragma unroll
        for (int g2 = 0; g2 < 2; ++g2) {
#pragma unroll
            for (int fh = 0; fh < 2; ++fh) {
                float4v hc = __builtin_amdgcn_mfma_f32_16x16x32_bf16(
                    fh ? w1f1 : w1f0, qfrag[g2], (float4v)0.0f, 0, 0, 0);
                unsigned int p0 = cvt_pk_bf16(fmaxf(hc[0], 0.f), fmaxf(hc[1], 0.f));
                unsigned int p1 = cvt_pk_bf16(fmaxf(hc[2], 0.f), fmaxf(hc[3], 0.f));
                int m   = wave * 32 + g2 * 16 + l16;
                int qph = (fh * 2 + (quad >> 1)) ^ hswz;
                unsigned long long pk = ((unsigned long long)p1 << 32) | p0;
                *(unsigned long long*)&Asm[buf][m * 32 + qph * 8 + (quad & 1) * 4] = pk;
            }
        }
    };

    float4v acc[32];
#pragma unroll
    for (int i = 0; i < 32; ++i) acc[i] = (float4v)0.0f;

    // conflict-free fragment loads + 32 MFMA from buffers [buf]
    auto compute = [&](int buf) __attribute__((always_inline)) {
        short8 af[4], bfr[8];
#pragma unroll
        for (int fm = 0; fm < 4; ++fm) {
            int row = wm * 64 + fm * 16 + l16;
            int qph = quad ^ ((row >> 1) & 3);
            af[fm] = *(const short8*)&Asm[buf][row * 32 + qph * 8];
        }
#pragma unroll
        for (int fn = 0; fn < 8; ++fn) {
            int row = wn * 128 + fn * 16 + l16;
            int qph = quad ^ ((row >> 1) & 3);
            bfr[fn] = *(const short8*)&Bsm[buf][row * 32 + qph * 8];
        }
        __builtin_amdgcn_s_setprio(1);
#pragma unroll
        for (int fm = 0; fm < 4; ++fm)
#pragma unroll
            for (int fn = 0; fn < 8; ++fn)
                acc[fm * 8 + fn] = __builtin_amdgcn_mfma_f32_16x16x32_bf16(
                    af[fm], bfr[fn], acc[fm * 8 + fn], 0, 0, 0);
        __builtin_amdgcn_s_setprio(0);
    };

    // ---- prologue: tile 0 ----
    {
        short8 w1f0, w1f1;
        loadW1(0, w1f0, w1f1);
        stageB(0, 0);
        hgen(0, w1f0, w1f1);
    }
    __syncthreads();        // vmcnt: B(0) landed; lgkm: h(0) visible

    // ---- pipelined main loop: 1 barrier per K-step ----
    // pair-unrolled so the buffer parity is a compile-time constant
    for (int kt = 0; kt < 62; kt += 2) {
        {   // step kt (cb=0): produce tile kt+1
            short8 w1f0, w1f1;
            loadW1((kt + 1) * BK, w1f0, w1f1);
            stageB((kt + 1) * BK, 1);
            compute(0);
            hgen(1, w1f0, w1f1);
        }
        __syncthreads();
        {   // step kt+1 (cb=1): produce tile kt+2
            short8 w1f0, w1f1;
            loadW1((kt + 2) * BK, w1f0, w1f1);
            stageB((kt + 2) * BK, 0);
            compute(1);
            hgen(0, w1f0, w1f1);
        }
        __syncthreads();
    }
    // kt = 62 (cb=0): produce last tile (63)
    {
        short8 w1f0, w1f1;
        loadW1(63 * BK, w1f0, w1f1);
        stageB(63 * BK, 1);
        compute(0);
        hgen(1, w1f0, w1f1);
    }
    __syncthreads();
    // kt = 63: tail, compute only
    compute(1);

    // ---- epilogue: D layout col=lane&15 (n), row=quad*4+reg (m) ----
    const int om = m0 + wm * 64;
    const int on = n0 + wn * 128;
#pragma unroll
    for (int fm = 0; fm < 4; ++fm) {
#pragma unroll
        for (int fn = 0; fn < 8; ++fn) {
            float4v v = acc[fm * 8 + fn];
            int rbase = om + fm * 16 + quad * 4;
            int c     = on + fn * 16 + l16;
#pragma unroll
            for (int r = 0; r < 4; ++r)
                out[(size_t)(rbase + r) * EMB + c] = v[r];
        }
    }
}

extern "C" void kernel_launch(void* const* d_in, const int* in_sizes, int n_in,
                              void* d_out, int out_size, void* d_ws, size_t ws_size,
                              hipStream_t stream) {
    const float* x     = (const float*)d_in[0];
    const float* theta = (const float*)d_in[1];
    const float* W1    = (const float*)d_in[2];
    const float* W2    = (const float*)d_in[3];
    float* out = (float*)d_out;

    unsigned int* w2b = (unsigned int*)d_ws;               // 2 MiB (bf16 bits)
    unsigned int* w1b = (unsigned int*)((char*)d_ws + (size_t)EMB * FFN * 2);  // 32 KB

    prep_w2<<<(EMB * FFN) / (256 * 4), 256, 0, stream>>>(W2, w2b);
    prep_w2<<<(FFN * NQ) / (256 * 4), 256, 0, stream>>>(W1, w1b);   // 16 blocks

    dim3 grid(M_TOTAL / BM, EMB / BN);         // 256 x 2 = 512 blocks, 2/CU
    ffq_main<<<grid, NTHREADS, 0, stream>>>(x, theta,
                                            (const unsigned short*)w1b,
                                            (const unsigned short*)w2b, out);
}